// Round 14
// baseline (126.443 us; speedup 1.0000x reference)
//
#include <hip/hip_runtime.h>
#include <hip/hip_bf16.h>

#define LL   2048
#define BB   4
#define DD   512
#define HH   8
#define DKK  64
#define WBAND 12
#define NBAND 25   // 2*WBAND+1

typedef __attribute__((ext_vector_type(8))) short  bf16x8;
typedef __attribute__((ext_vector_type(4))) float  f32x4;

#define WOUT_F4    4194304   // B*L*L/4 total f32x4 in wout
#define ZSPLIT_F4  2621440   // f4 zeroed by proj's zero blocks (40 MB)

// Q pre-scale folds softmax 1/8 AND log2(e): exp(s/8) == 2^(s * 0.125*log2e)
#define QSCALE 0.18033688f
// exp(-0.5 d^2) == 2^(-0.72134752 d^2)
#define DIST_C (-0.72134752f)

static __device__ __forceinline__ float bf2f(unsigned short u) {
    union { unsigned int i; float f; } c; c.i = ((unsigned int)u) << 16; return c.f;
}
static __device__ __forceinline__ unsigned short f2bf(float f) {
    union { float f; unsigned int i; } c; c.f = f;
    unsigned int x = c.i;
    return (unsigned short)((x + 0x7fffu + ((x >> 16) & 1u)) >> 16);
}
static __device__ __forceinline__ unsigned short f2bf_rn(float f) {
    __hip_bfloat16 h = __float2bfloat16(f);
    return reinterpret_cast<unsigned short&>(h);
}
static __device__ __forceinline__ bf16x8 pack8(float4 x0, float4 x1) {
    bf16x8 r;
    r[0] = (short)f2bf_rn(x0.x); r[1] = (short)f2bf_rn(x0.y);
    r[2] = (short)f2bf_rn(x0.z); r[3] = (short)f2bf_rn(x0.w);
    r[4] = (short)f2bf_rn(x1.x); r[5] = (short)f2bf_rn(x1.y);
    r[6] = (short)f2bf_rn(x1.z); r[7] = (short)f2bf_rn(x1.w);
    return r;
}

// ---------------------------------------------------------------------------
// proj: Out[b,h,l,dk] = ((X @ Wm^T)[m,n] + bias[n]) * scale.
// Compute blocks x<64; NT zero blocks x>=64 (first 40 MB of wout).
// ---------------------------------------------------------------------------
__global__ __launch_bounds__(256) void proj_mfma(
    const float* __restrict__ Xq, const float* __restrict__ Xk,
    const float* __restrict__ Wqf, const float* __restrict__ Wkf,
    const float* __restrict__ bq, const float* __restrict__ bk,
    unsigned short* __restrict__ Qh, unsigned short* __restrict__ Kh,
    float* __restrict__ wout)
{
    __shared__ unsigned short Asm[128 * 64];
    __shared__ unsigned short Bsm[128 * 64];

    const int t = threadIdx.x;

    if (blockIdx.x >= 64) {                 // ---- zero block (NT) ----
        const int zb  = (blockIdx.z * 4 + blockIdx.y) * 32 + (blockIdx.x - 64);
        const int gid = zb * 256 + t;
        const f32x4 zz = {0.f, 0.f, 0.f, 0.f};
#pragma unroll
        for (int i = 0; i < 40; ++i)
            __builtin_nontemporal_store(zz,
                (f32x4*)&wout[((size_t)gid + (size_t)i * 65536) * 4]);
        return;
    }

    const int which = blockIdx.z;
    const float* X   = which ? Xk  : Xq;
    const float* Wm  = which ? Wkf : Wqf;
    const float* bias = which ? bk : bq;
    unsigned short* Out = which ? Kh : Qh;
    const float scale   = which ? 1.0f : QSCALE;

    const int w  = t >> 6;
    const int l  = t & 63;
    const int wr = w >> 1;
    const int wc = w & 1;
    const int mb = blockIdx.x * 128;
    const int nb = blockIdx.y * 128;
    const int lr = l & 15;
    const int lk = (l >> 4) * 8;

    int srow[4], scol[4], sswz[4];
#pragma unroll
    for (int i = 0; i < 4; ++i) {
        const int flat = t + i * 256;
        srow[i] = flat >> 3;
        scol[i] = (flat & 7) * 8;
        sswz[i] = (srow[i] * 64 + scol[i]) ^ ((srow[i] & 7) << 3);
    }

    float4 ra[4][2], rb[4][2];
#pragma unroll
    for (int i = 0; i < 4; ++i) {
        const float* pa = &X [(size_t)(mb + srow[i]) * DD + scol[i]];
        const float* pb = &Wm[(size_t)(nb + srow[i]) * DD + scol[i]];
        ra[i][0] = *(const float4*)pa; ra[i][1] = *(const float4*)(pa + 4);
        rb[i][0] = *(const float4*)pb; rb[i][1] = *(const float4*)(pb + 4);
    }

    f32x4 acc[4][4] = {};

    for (int k0 = 0; k0 < DD; k0 += 64) {
        __syncthreads();
#pragma unroll
        for (int i = 0; i < 4; ++i) {
            *(bf16x8*)&Asm[sswz[i]] = pack8(ra[i][0], ra[i][1]);
            *(bf16x8*)&Bsm[sswz[i]] = pack8(rb[i][0], rb[i][1]);
        }
        if (k0 + 64 < DD) {
#pragma unroll
            for (int i = 0; i < 4; ++i) {
                const float* pa = &X [(size_t)(mb + srow[i]) * DD + k0 + 64 + scol[i]];
                const float* pb = &Wm[(size_t)(nb + srow[i]) * DD + k0 + 64 + scol[i]];
                ra[i][0] = *(const float4*)pa; ra[i][1] = *(const float4*)(pa + 4);
                rb[i][0] = *(const float4*)pb; rb[i][1] = *(const float4*)(pb + 4);
            }
        }
        __syncthreads();

#pragma unroll
        for (int kk = 0; kk < 64; kk += 32) {
            bf16x8 af[4], bfr[4];
#pragma unroll
            for (int mi = 0; mi < 4; ++mi) {
                const int row = wr * 64 + 16 * mi + lr;
                af[mi] = *(const bf16x8*)&Asm[(row * 64 + kk + lk) ^ ((row & 7) << 3)];
            }
#pragma unroll
            for (int ni = 0; ni < 4; ++ni) {
                const int row = wc * 64 + 16 * ni + lr;
                bfr[ni] = *(const bf16x8*)&Bsm[(row * 64 + kk + lk) ^ ((row & 7) << 3)];
            }
#pragma unroll
            for (int mi = 0; mi < 4; ++mi)
#pragma unroll
                for (int ni = 0; ni < 4; ++ni)
                    acc[mi][ni] = __builtin_amdgcn_mfma_f32_16x16x32_bf16(
                        af[mi], bfr[ni], acc[mi][ni], 0, 0, 0);
        }
    }

#pragma unroll
    for (int ni = 0; ni < 4; ++ni) {
        const int n  = nb + wc * 64 + 16 * ni + lr;
        const int h  = n >> 6;
        const int dk = n & 63;
        const float bs = bias[n];
#pragma unroll
        for (int mi = 0; mi < 4; ++mi)
#pragma unroll
            for (int j = 0; j < 4; ++j) {
                const int m    = mb + wr * 64 + 16 * mi + (l >> 4) * 4 + j;
                const int lseq = m >> 2;
                const int bidx = m & 3;
                Out[(((size_t)(bidx * HH + h)) * LL + lseq) * DKK + dk] =
                    f2bf((acc[mi][ni][j] + bs) * scale);
            }
    }
}

// ---------------------------------------------------------------------------
// scorez v3: Z[bh,q] = sum_k 2^( Qh[bh,q] . Kh[bh,k] )  (Q pre-scaled QSCALE)
// LDS-staged streaming GEMM (2-phase): waves split q (16 rows each); block
// cooperatively stages 128-row K tiles (16 KB, contiguous) into dbuf LDS
// with XOR swizzle (16B-block ^= row&7, write & read sides); per tile:
// issue next tile's 4 coalesced loads -> 16 ds_read_b128 + 16 MFMA +
// 32 exp2 per wave -> ds_write staged regs -> barrier.
// Compute blocks x<32; NT zero blocks x in [32,40). grid (40, 32).
// ---------------------------------------------------------------------------
__global__ __launch_bounds__(256) void scorez_mfma(
    const unsigned short* __restrict__ Qh, const unsigned short* __restrict__ Kh,
    float* __restrict__ Z, float* __restrict__ wout)
{
    __shared__ unsigned short Ksm[2][128 * 64];
    __shared__ float Zp[4][16];
    const int t = threadIdx.x;

    if (blockIdx.x >= 32) {                 // ---- zero block (NT) ----
        const int zb  = blockIdx.y * 8 + (blockIdx.x - 32);
        const int gid = zb * 256 + t;
        const f32x4 zz = {0.f, 0.f, 0.f, 0.f};
#pragma unroll
        for (int i = 0; i < 24; ++i)
            __builtin_nontemporal_store(zz,
                (f32x4*)&wout[((size_t)ZSPLIT_F4 + (size_t)gid + (size_t)i * 65536) * 4]);
        return;
    }

    const int w  = t >> 6;
    const int l  = t & 63;
    const int bh = blockIdx.y;
    const int qb = blockIdx.x * 64;
    const int lr = l & 15;
    const int hi = l >> 4;              // 0..3
    const int lk = hi * 8;
    const unsigned short* Qp = Qh + (size_t)bh * LL * DKK;
    const unsigned short* Kp = Kh + (size_t)bh * LL * DKK;

    // Q-frag: wave w owns q-rows [qb+16w, qb+16w+16)
    bf16x8 qa[2];
#pragma unroll
    for (int s = 0; s < 2; ++s)
        qa[s] = *(const bf16x8*)&Qp[(size_t)(qb + 16 * w + lr) * DKK + 32 * s + lk];

    // staging: thread t covers 16B-blocks s = t + 256*i of the 16 KB tile;
    // LDS dest block = s ^ ((s>>3)&7)  (row = s>>3, 8 blocks/row)
    int sdst[4];
#pragma unroll
    for (int i = 0; i < 4; ++i) {
        const int s = t + 256 * i;
        sdst[i] = (s ^ ((s >> 3) & 7)) * 8;   // bf16-element index
    }

    // read-side swizzled addresses (element index), per kf & khalf:
    // row r = kf*16+lr, block = r*8 + khalf*4 + hi, ^ (lr&7)
    // prologue: stage tile 0
    bf16x8 stg[4];
#pragma unroll
    for (int i = 0; i < 4; ++i)
        stg[i] = *(const bf16x8*)&Kp[(size_t)(t + 256 * i) * 8];
#pragma unroll
    for (int i = 0; i < 4; ++i)
        *(bf16x8*)&Ksm[0][sdst[i]] = stg[i];
    __syncthreads();

    float zacc[4] = {0.f, 0.f, 0.f, 0.f};
    int cur = 0;

    for (int tt = 0; tt < 16; ++tt) {
        const bool has = (tt + 1) < 16;
        if (has) {
            const size_t gbase = (size_t)(tt + 1) * 128 * DKK;   // elements
#pragma unroll
            for (int i = 0; i < 4; ++i)
                stg[i] = *(const bf16x8*)&Kp[gbase + (size_t)(t + 256 * i) * 8];
        }
#pragma unroll
        for (int kf = 0; kf < 8; ++kf) {
            const int r  = kf * 16 + lr;
            const int b0i = (((r * 8) + 0 * 4 + hi) ^ (lr & 7)) * 8;
            const int b1i = (((r * 8) + 1 * 4 + hi) ^ (lr & 7)) * 8;
            const bf16x8 kb0 = *(const bf16x8*)&Ksm[cur][b0i];
            const bf16x8 kb1 = *(const bf16x8*)&Ksm[cur][b1i];
            f32x4 acc = {0.f, 0.f, 0.f, 0.f};
            acc = __builtin_amdgcn_mfma_f32_16x16x32_bf16(qa[0], kb0, acc, 0, 0, 0);
            acc = __builtin_amdgcn_mfma_f32_16x16x32_bf16(qa[1], kb1, acc, 0, 0, 0);
#pragma unroll
            for (int j = 0; j < 4; ++j)
                zacc[j] += __builtin_amdgcn_exp2f(acc[j]);
        }
        if (has) {
#pragma unroll
            for (int i = 0; i < 4; ++i)
                *(bf16x8*)&Ksm[cur ^ 1][sdst[i]] = stg[i];
        }
        __syncthreads();
        cur ^= 1;
    }

    // reduce over the 16 k-cols (lr lanes); D-frag: col=lr, row=hi*4+j
#pragma unroll
    for (int m = 1; m <= 8; m <<= 1)
#pragma unroll
        for (int j = 0; j < 4; ++j)
            zacc[j] += __shfl_xor(zacc[j], m, 64);

    if (lr == 0) {
#pragma unroll
        for (int j = 0; j < 4; ++j)
            Zp[w][hi * 4 + j] = zacc[j];
    }
    __syncthreads();
    if (t < 64)
        Z[(size_t)bh * LL + qb + t] = Zp[t >> 4][t & 15];
}

// ---------------------------------------------------------------------------
// weights: one WAVE per (b,q): band weights -> wgtbuf + scatter into the
// (already-zeroed) dense wout row. exp2 consistent with scorez.
// ---------------------------------------------------------------------------
__global__ __launch_bounds__(256) void weights_kernel(
    const unsigned short* __restrict__ Qh, const unsigned short* __restrict__ Kh,
    const float* __restrict__ Z, float* __restrict__ wgtbuf,
    float* __restrict__ wout)
{
    const int t = threadIdx.x;
    const int w = t >> 6;
    const int l = t & 63;
    const int idx = blockIdx.x * 4 + w;       // idx = b*L + q
    const int b = idx >> 11;
    const int q = idx & 2047;
    const int h = l >> 3;
    const int jslot = l & 7;

    bf16x8 qv[8];
    {
        const bf16x8* qp = (const bf16x8*)&Qh[(((size_t)b * HH + h) * LL + q) * DKK];
#pragma unroll
        for (int i = 0; i < 8; ++i) qv[i] = qp[i];
    }
    const float zinv = 1.0f / Z[((size_t)b * HH + h) * LL + q];

    float e[4];
#pragma unroll
    for (int c = 0; c < 4; ++c) {
        const int j = jslot + 8 * c;
        const int k = q - WBAND + j;
        float a = 0.f;
        if (j < NBAND && k >= 0 && k < LL) {
            const bf16x8* kp = (const bf16x8*)&Kh[(((size_t)b * HH + h) * LL + k) * DKK];
            float s = 0.f;
#pragma unroll
            for (int i = 0; i < 8; ++i) {
                const bf16x8 ka = kp[i];
#pragma unroll
                for (int ee = 0; ee < 8; ++ee)
                    s += bf2f((unsigned short)qv[i][ee]) * bf2f((unsigned short)ka[ee]);
            }
            a = __builtin_amdgcn_exp2f(s) * zinv;
        }
        e[c] = a;
    }

#pragma unroll
    for (int m = 8; m <= 32; m <<= 1)
#pragma unroll
        for (int c = 0; c < 4; ++c)
            e[c] += __shfl_xor(e[c], m, 64);

    float att[4];
    float part = 0.f;
#pragma unroll
    for (int c = 0; c < 4; ++c) {
        const int j = jslot + 8 * c;
        const float dd = (float)(j - WBAND);
        att[c] = (j < NBAND) ? e[c] * __builtin_amdgcn_exp2f(DIST_C * dd * dd) : 0.f;
        part += att[c];
    }
#pragma unroll
    for (int m = 1; m <= 4; m <<= 1)
        part += __shfl_xor(part, m, 64);
    const float winv = 1.0f / part;

    if (h == 0) {
        float* wrow = &wout[((size_t)b * LL + q) * LL];
#pragma unroll
        for (int c = 0; c < 4; ++c) {
            const int j = jslot + 8 * c;
            if (j < NBAND) {
                const float wv = att[c] * winv;
                wgtbuf[(size_t)idx * 32 + j] = wv;
                const int k = q - WBAND + j;
                if (k >= 0 && k < LL) wrow[k] = wv;
            }
        }
    }
}

// ---------------------------------------------------------------------------
// out: grid (L/8, B). Register sliding window over v; plain stores.
// ---------------------------------------------------------------------------
__global__ __launch_bounds__(256) void out_kernel(
    const float* __restrict__ wgtbuf, const float* __restrict__ v,
    float* __restrict__ out)
{
    __shared__ float lw[8][NBAND];
    const int t  = threadIdx.x;
    const int q0 = blockIdx.x * 8;
    const int b  = blockIdx.y;

    if (t < 8 * NBAND) {
        const int qq = t / NBAND;
        const int j  = t - qq * NBAND;
        lw[qq][j] = wgtbuf[((size_t)b * LL + q0 + qq) * 32 + j];
    }
    __syncthreads();

    const int qsub = t >> 7;
    const int d4   = t & 127;
    const int qs   = q0 + qsub * 4;
    const int kbase = qs - WBAND;
    f32x4 acc[4] = {{0,0,0,0},{0,0,0,0},{0,0,0,0},{0,0,0,0}};
#pragma unroll
    for (int kk = 0; kk < 28; ++kk) {
        const int k = kbase + kk;
        f32x4 vv = {0.f, 0.f, 0.f, 0.f};
        if (k >= 0 && k < LL)
            vv = *(const f32x4*)&v[((size_t)k * BB + b) * DD + d4 * 4];
#pragma unroll
        for (int qi = 0; qi < 4; ++qi) {
            const int j = kk - qi;
            if (j >= 0 && j < NBAND) {
                const float wv = lw[qsub * 4 + qi][j];
                acc[qi][0] += wv * vv[0]; acc[qi][1] += wv * vv[1];
                acc[qi][2] += wv * vv[2]; acc[qi][3] += wv * vv[3];
            }
        }
    }
#pragma unroll
    for (int qi = 0; qi < 4; ++qi) {
        const int q = qs + qi;
        *(f32x4*)&out[((size_t)q * BB + b) * DD + d4 * 4] = acc[qi];
    }
}

// ---------------------------------------------------------------------------
extern "C" void kernel_launch(void* const* d_in, const int* in_sizes, int n_in,
                              void* d_out, int out_size, void* d_ws, size_t ws_size,
                              hipStream_t stream) {
    const float* q  = (const float*)d_in[0];
    const float* k  = (const float*)d_in[1];
    const float* v  = (const float*)d_in[2];
    const float* Wq = (const float*)d_in[3];
    const float* bq = (const float*)d_in[4];
    const float* Wk = (const float*)d_in[5];
    const float* bk = (const float*)d_in[6];

    float* out  = (float*)d_out;                       // [L,B,D]
    float* wout = out + (size_t)LL * BB * DD;          // [B,L,L]

    unsigned short* Qh = (unsigned short*)d_ws;                 // bf16 [B,H,L,DK] 8 MB
    unsigned short* Kh = Qh + (size_t)BB * HH * LL * DKK;       // bf16 8 MB
    float* Z      = (float*)(Kh + (size_t)BB * HH * LL * DKK);  // [B*H*L] 256 KB
    float* wgtbuf = Z + (size_t)BB * HH * LL;                   // [B*L][32] 1 MB

    proj_mfma<<<dim3(64 + 32, DD / 128, 2), 256, 0, stream>>>(
        q, k, Wq, Wk, bq, bk, Qh, Kh, wout);

    scorez_mfma<<<dim3(32 + 8, BB * HH), 256, 0, stream>>>(Qh, Kh, Z, wout);

    weights_kernel<<<BB * LL / 4, 256, 0, stream>>>(Qh, Kh, Z, wgtbuf, wout);

    out_kernel<<<dim3(LL / 8, BB), 256, 0, stream>>>(wgtbuf, v, out);
}